// Round 2
// 497.861 us; speedup vs baseline: 1.0924x; 1.0924x over previous
//
#include <hip/hip_runtime.h>
#include <cstdint>
#include <cstddef>

#define S_LEN 2048
#define DM 512
#define NH 8
#define DK 64
#define DFF 2048
#define BATCH 2
#define NROWS (BATCH*S_LEN)   // 4096
#define BHN (BATCH*NH)        // 16

// masked score in log2 domain: -1e9 * log2(e)
#define MASKED_L2 (-1.4426950408889634e9f)
// (1/sqrt(64)) * log2(e), folded into Q
#define QSCALE 0.18033688011112042f

typedef __attribute__((ext_vector_type(8))) _Float16 f16x8;
typedef __attribute__((ext_vector_type(4))) _Float16 f16x4;
typedef __attribute__((ext_vector_type(4))) float f32x4;

#define MFMA(a,b,c)   __builtin_amdgcn_mfma_f32_16x16x32_f16(a,b,c,0,0,0)
#define MFMA16(a,b,c) __builtin_amdgcn_mfma_f32_16x16x16f16(a,b,c,0,0,0)

__device__ __forceinline__ unsigned short f2h(float x){
  union{ _Float16 h; unsigned short u; } c; c.h = (_Float16)x; return c.u;
}
// XOR swizzle on 16B granules; rows of 64 halves
__device__ __forceinline__ int sw64(int r, int c){
  return r*64 + ((((c>>3) ^ r) & 7)<<3) + (c&7);
}
// rows of 32 halves (BK=32 GEMM tiles)
__device__ __forceinline__ int sw32(int r, int c){
  return r*32 + ((((c>>3) ^ r) & 3)<<3) + (c&7);
}

// ---------------------------------------------------------------------------
// prep: z=0..5 transpose+fp16 weights, z=6 x->fp16, z=7 mask bit-pack
// grid (1024, 8), block 256
// ---------------------------------------------------------------------------
__global__ __launch_bounds__(256) void prep_kernel(
    const float* __restrict__ x, const int* __restrict__ mask,
    const float* __restrict__ Wq, const float* __restrict__ Wk,
    const float* __restrict__ Wv, const float* __restrict__ Wo,
    const float* __restrict__ W1, const float* __restrict__ W2,
    unsigned short* __restrict__ xb,
    unsigned short* __restrict__ wqT, unsigned short* __restrict__ wkT,
    unsigned short* __restrict__ wvT, unsigned short* __restrict__ woT,
    unsigned short* __restrict__ w1T, unsigned short* __restrict__ w2T,
    unsigned* __restrict__ maskw)
{
  const int z = blockIdx.y;
  const int t = blockIdx.x;
  const int tid = threadIdx.x;
  if (z < 6){
    const float* W; unsigned short* WT; int K, N;
    switch(z){
      case 0: W=Wq; WT=wqT; K=512;  N=512;  break;
      case 1: W=Wk; WT=wkT; K=512;  N=512;  break;
      case 2: W=Wv; WT=wvT; K=512;  N=512;  break;
      case 3: W=Wo; WT=woT; K=512;  N=512;  break;
      case 4: W=W1; WT=w1T; K=512;  N=2048; break;
      default:W=W2; WT=w2T; K=2048; N=512;  break;
    }
    const int ntiles = N>>5, ktiles = K>>5;
    if (t >= ntiles*ktiles) return;
    const int kt = t / ntiles, nt = t - kt*ntiles;
    __shared__ float tile[32][33];
    const int tx = tid & 31, ty = tid >> 5;
    #pragma unroll
    for (int i=0;i<4;i++){
      int r = ty + i*8;
      tile[r][tx] = W[(size_t)(kt*32 + r)*N + nt*32 + tx];
    }
    __syncthreads();
    #pragma unroll
    for (int i=0;i<4;i++){
      int r = ty + i*8;
      WT[(size_t)(nt*32 + r)*K + kt*32 + tx] = f2h(tile[tx][r]);
    }
  } else if (z == 6){
    // x (2,097,152 floats) -> fp16 ; 1024 blocks * 256 thr * 8 elems
    size_t base = (size_t)t*2048 + (size_t)tid*8;
    float4 a = *(const float4*)(x + base);
    float4 b = *(const float4*)(x + base + 4);
    union{ unsigned short h[8]; uint4 v; } pk;
    pk.h[0]=f2h(a.x); pk.h[1]=f2h(a.y); pk.h[2]=f2h(a.z); pk.h[3]=f2h(a.w);
    pk.h[4]=f2h(b.x); pk.h[5]=f2h(b.y); pk.h[6]=f2h(b.z); pk.h[7]=f2h(b.w);
    *(uint4*)(xb + base) = pk.v;
  } else {
    // pack mask [2048][2048] ints -> [2048][64] bit words
    if (t >= 512) return;
    const int gid = t*256 + tid;             // 0..131071
    const int row = gid >> 6, w = gid & 63;
    const int4* mp = (const int4*)(mask + (size_t)row*2048 + w*32);
    unsigned word = 0;
    #pragma unroll
    for (int j=0;j<8;j++){
      int4 v = mp[j];
      word |= (unsigned)(v.x!=0) << (j*4+0);
      word |= (unsigned)(v.y!=0) << (j*4+1);
      word |= (unsigned)(v.z!=0) << (j*4+2);
      word |= (unsigned)(v.w!=0) << (j*4+3);
    }
    maskw[gid] = word;
  }
}

// ---------------------------------------------------------------------------
// GEMM: C[M,64.. per block 64x64] = A[M,KD] @ BT[N,KD]^T  (fp16 in, fp32 acc)
// EPI 0: QKV (z: 0=Q scaled row-major, 1=K row-major, 2=V TRANSPOSED [bh][d][s])
// EPI 1: out fp32 = acc + bias[col] + resid[row,col]
// EPI 2: out fp16 = gelu(acc + bias[col]) stride DFF
// ---------------------------------------------------------------------------
template<int KD, int EPI>
__global__ __launch_bounds__(256) void gemm_kernel(
    const unsigned short* __restrict__ A,
    const unsigned short* __restrict__ BT0,
    const unsigned short* __restrict__ BT1,
    const unsigned short* __restrict__ BT2,
    const float* __restrict__ bias,
    const float* __restrict__ resid,
    float* __restrict__ outf,
    unsigned short* __restrict__ ob0,
    unsigned short* __restrict__ ob1,
    unsigned short* __restrict__ ob2)
{
  const unsigned short* BT = BT0;
  unsigned short* outb = ob0;
  float scale = 1.0f;
  bool vtrans = false;
  if (EPI == 0){
    const int z = blockIdx.z;
    if (z == 0) scale = QSCALE;
    else if (z == 1){ BT = BT1; outb = ob1; }
    else            { BT = BT2; outb = ob2; vtrans = true; }
  }
  const int m0 = blockIdx.x*64, n0 = blockIdx.y*64;
  const int tid = threadIdx.x;
  const int wid = tid>>6, l = tid&63, quad = l>>4, lc = l&15;
  const int wm = wid&1, wn = wid>>1;
  __shared__ __align__(16) unsigned short As[2][64*32];
  __shared__ __align__(16) unsigned short Bs[2][64*32];
  const int sr = tid>>2, sc = (tid&3)*8;
  const unsigned short* Ap = A  + (size_t)(m0+sr)*KD + sc;
  const unsigned short* Bp = BT + (size_t)(n0+sr)*KD + sc;
  {
    uint4 va = *(const uint4*)Ap;
    uint4 vb = *(const uint4*)Bp;
    *(uint4*)&As[0][sw32(sr,sc)] = va;
    *(uint4*)&Bs[0][sw32(sr,sc)] = vb;
  }
  f32x4 acc00={0,0,0,0}, acc01={0,0,0,0}, acc10={0,0,0,0}, acc11={0,0,0,0};
  const int ar0 = wm*32 + lc, ar1 = wm*32 + 16 + lc;
  const int br0 = wn*32 + lc, br1 = wn*32 + 16 + lc;
  __syncthreads();
  constexpr int NK = KD/32;
  for (int kk=0; kk<NK; kk++){
    const int cur = kk & 1;
    if (kk+1 < NK){
      uint4 va = *(const uint4*)(Ap + (size_t)(kk+1)*32);
      uint4 vb = *(const uint4*)(Bp + (size_t)(kk+1)*32);
      *(uint4*)&As[cur^1][sw32(sr,sc)] = va;
      *(uint4*)&Bs[cur^1][sw32(sr,sc)] = vb;
    }
    f16x8 a0 = *(const f16x8*)&As[cur][sw32(ar0, quad*8)];
    f16x8 a1 = *(const f16x8*)&As[cur][sw32(ar1, quad*8)];
    f16x8 b0 = *(const f16x8*)&Bs[cur][sw32(br0, quad*8)];
    f16x8 b1 = *(const f16x8*)&Bs[cur][sw32(br1, quad*8)];
    acc00 = MFMA(a0,b0,acc00);
    acc01 = MFMA(a0,b1,acc01);
    acc10 = MFMA(a1,b0,acc10);
    acc11 = MFMA(a1,b1,acc11);
    __syncthreads();
  }
  f32x4 accs[2][2] = {{acc00,acc01},{acc10,acc11}};
  #pragma unroll
  for (int mt=0;mt<2;mt++){
    #pragma unroll
    for (int nt=0;nt<2;nt++){
      f32x4 v = accs[mt][nt];
      const int col  = n0 + wn*32 + nt*16 + lc;
      const int row0 = m0 + wm*32 + mt*16 + quad*4;
      if (EPI == 0 && vtrans){
        // V transposed: v^T[(b*NH+h)][d][s], 4 consecutive s = 8B store
        const int h = col>>6, d = col&63, b = row0>>11, s0 = row0&2047;
        union{ unsigned short h4[4]; uint2 u; } pk;
        #pragma unroll
        for (int r=0;r<4;r++) pk.h4[r] = f2h(v[r]);
        *(uint2*)(outb + (((size_t)(b*NH + h))*DK + d)*S_LEN + s0) = pk.u;
      } else {
        #pragma unroll
        for (int r=0;r<4;r++){
          const int row = row0 + r;
          const float val = v[r];
          if (EPI == 0){
            const int h = col>>6, d = col&63, b = row>>11, s = row&2047;
            outb[(((size_t)(b*NH + h))*S_LEN + s)*DK + d] = f2h(val*scale);
          } else if (EPI == 1){
            const size_t idx = (size_t)row*DM + col;
            outf[idx] = val + bias[col] + resid[idx];
          } else {
            const float xx = val + bias[col];
            const float gg = 0.5f*xx*(1.0f + erff(xx*0.70710678118654752f));
            outb[(size_t)row*DFF + col] = f2h(gg);
          }
        }
      }
    }
  }
}

// ---------------------------------------------------------------------------
// Fused attention: loop1 = online softmax stats (swapped QK^T -> per-lane
// row-local), loop2 = recompute scores, write probs (fp32, nontemporal),
// P@V via 16x16x16 MFMA with P fed DIRECTLY from accumulator registers.
// V arrives pre-transposed [bh][d][s]; staged into conflict-free
// [g=k>>2][(d^g)&63][k&3] LDS layout, read as ds_read_b64.
// grid (32, 16), block 256 (4 waves x 16 q-rows each)
// ---------------------------------------------------------------------------
__global__ __launch_bounds__(256) void kattn_kernel(
    const unsigned short* __restrict__ qw,
    const unsigned short* __restrict__ kw,
    const unsigned short* __restrict__ vwT,
    const unsigned* __restrict__ maskw,
    float* __restrict__ attn,
    unsigned short* __restrict__ ctx)
{
  const int bh = blockIdx.y, q0 = blockIdx.x*64;
  const int tid = threadIdx.x, wid = tid>>6, l = tid&63, quad = l>>4, lc = l&15;
  __shared__ __align__(16) unsigned short Qs[64*64];
  __shared__ __align__(16) unsigned short Ks[2][64*64];
  __shared__ __align__(16) unsigned short Vs[2][64*64];  // [g][entry][4]
  const unsigned short* qbase = qw + ((size_t)bh*S_LEN + q0)*DK;
  const unsigned short* kbase = kw + (size_t)bh*S_LEN*DK;
  const unsigned short* vbase = vwT + (size_t)bh*DK*S_LEN;

  auto stageK = [&](unsigned short* dst, const unsigned short* src){
    #pragma unroll
    for (int i=0;i<2;i++){
      const int idx = tid + i*256, r = idx>>3, c0 = (idx&7)*8;
      *(uint4*)&dst[sw64(r,c0)] = *(const uint4*)(src + (size_t)r*DK + c0);
    }
  };
  // src = v^T row d, 64-col tile base; 8 halves -> two 4-half groups
  auto stageV = [&](unsigned short* dst, const unsigned short* src){
    #pragma unroll
    for (int i=0;i<2;i++){
      const int idx = tid + i*256, d = idx>>3, k0 = (idx&7)*8;
      union { uint4 u; uint2 v2[2]; } U;
      U.u = *(const uint4*)(src + (size_t)d*S_LEN + k0);
      const int g0 = k0>>2;
      *(uint2*)&dst[(g0  )*256 + (((d ^  g0   )&63)<<2)] = U.v2[0];
      *(uint2*)&dst[(g0+1)*256 + (((d ^ (g0+1))&63)<<2)] = U.v2[1];
    }
  };

  // stage Q + K tile 0
  #pragma unroll
  for (int i=0;i<2;i++){
    const int idx = tid + i*256, r = idx>>3, c0 = (idx&7)*8;
    *(uint4*)&Qs[sw64(r,c0)] = *(const uint4*)(qbase + (size_t)r*DK + c0);
  }
  stageK(Ks[0], kbase);
  __syncthreads();

  // Q fragments (B-operand: row = lane&15 = q, k = quad*8+j)
  f16x8 bQ0, bQ1;
  {
    const int r = wid*16 + lc;
    bQ0 = *(const f16x8*)&Qs[sw64(r, quad*8)];
    bQ1 = *(const f16x8*)&Qs[sw64(r, 32 + quad*8)];
  }
  const int rowq = q0 + wid*16 + lc;
  const unsigned* mrow = maskw + (size_t)rowq*64;

  // ---- loop 1: stats (each lane covers k = quad*4+r within each 16-chunk) --
  float m = -3e38f, ls = 0.f;
  for (int c=0;c<32;c++){
    const int cur = c & 1;
    if (c+1 < 32) stageK(Ks[cur^1], kbase + (size_t)(c+1)*64*DK);
    const uint2 mw = *(const uint2*)(mrow + c*2);
    float sv[4][4];
    __builtin_amdgcn_s_setprio(1);
    #pragma unroll
    for (int nt=0; nt<4; nt++){
      f16x8 aK0 = *(const f16x8*)&Ks[cur][sw64(nt*16+lc, quad*8)];
      f16x8 aK1 = *(const f16x8*)&Ks[cur][sw64(nt*16+lc, 32+quad*8)];
      f32x4 s = {0,0,0,0};
      s = MFMA(aK0, bQ0, s);   // swapped: D[k][q], col=lane&15=q
      s = MFMA(aK1, bQ1, s);
      const unsigned w = (nt<2) ? mw.x : mw.y;
      #pragma unroll
      for (int r=0;r<4;r++){
        const int sh = (nt&1)*16 + quad*4 + r;
        sv[nt][r] = ((w>>sh)&1u) ? s[r] : MASKED_L2;
      }
    }
    __builtin_amdgcn_s_setprio(0);
    float mc = sv[0][0];
    #pragma unroll
    for (int nt=0;nt<4;nt++)
      #pragma unroll
      for (int r=0;r<4;r++) mc = fmaxf(mc, sv[nt][r]);
    const float m2 = fmaxf(m, mc);
    float add = 0.f;
    #pragma unroll
    for (int nt=0;nt<4;nt++)
      #pragma unroll
      for (int r=0;r<4;r++) add += __builtin_exp2f(sv[nt][r]-m2);
    ls = ls*__builtin_exp2f(m-m2) + add;
    m = m2;
    __syncthreads();
  }
  // combine the 4 quads (same q lives at lane, lane^16, lane^32, lane^48)
  #pragma unroll
  for (int o=16;o<64;o<<=1){
    const float mo = __shfl_xor(m, o, 64);
    const float lo = __shfl_xor(ls, o, 64);
    const float m2 = fmaxf(m, mo);
    ls = ls*__builtin_exp2f(m-m2) + lo*__builtin_exp2f(mo-m2);
    m = m2;
  }
  const float li = 1.0f/ls;

  // ---- loop 2: probs + P@V ------------------------------------------------
  stageK(Ks[0], kbase);
  stageV(Vs[0], vbase);
  f32x4 O[4] = {{0,0,0,0},{0,0,0,0},{0,0,0,0},{0,0,0,0}};  // O^T tiles, dt=d/16
  float* arow = attn + (size_t)bh*S_LEN*S_LEN + (size_t)rowq*S_LEN;
  __syncthreads();
  for (int c=0;c<32;c++){
    const int cur = c & 1;
    if (c+1 < 32){
      stageK(Ks[cur^1], kbase + (size_t)(c+1)*64*DK);
      stageV(Vs[cur^1], vbase + (size_t)(c+1)*64);
    }
    const uint2 mw = *(const uint2*)(mrow + c*2);
    __builtin_amdgcn_s_setprio(1);
    #pragma unroll
    for (int nt=0; nt<4; nt++){
      f16x8 aK0 = *(const f16x8*)&Ks[cur][sw64(nt*16+lc, quad*8)];
      f16x8 aK1 = *(const f16x8*)&Ks[cur][sw64(nt*16+lc, 32+quad*8)];
      f32x4 s = {0,0,0,0};
      s = MFMA(aK0, bQ0, s);
      s = MFMA(aK1, bQ1, s);
      const unsigned w = (nt<2) ? mw.x : mw.y;
      f32x4 pv;
      f16x4 bP;
      #pragma unroll
      for (int r=0;r<4;r++){
        const int sh = (nt&1)*16 + quad*4 + r;
        const float se = ((w>>sh)&1u) ? s[r] : MASKED_L2;
        const float p  = __builtin_exp2f(se - m) * li;
        pv[r] = p;
        bP[r] = (_Float16)p;
      }
      __builtin_nontemporal_store(pv, (f32x4*)(arow + (size_t)c*64 + nt*16 + quad*4));
      const int g = nt*4 + quad;
      #pragma unroll
      for (int dt=0; dt<4; dt++){
        f16x4 aV = *(const f16x4*)&Vs[cur][g*256 + ((((dt*16+lc) ^ g)&63)<<2)];
        O[dt] = MFMA16(aV, bP, O[dt]);   // D[d][q], col=lane&15=q
      }
    }
    __builtin_amdgcn_s_setprio(0);
    __syncthreads();
  }
  // ctx write: O^T tile dt holds d = dt*16 + quad*4 + r at col q = lc
  const int b = bh>>3, h = bh&7;
  unsigned short* cb = ctx + ((size_t)b*S_LEN + rowq)*DM + h*DK + quad*4;
  #pragma unroll
  for (int dt=0; dt<4; dt++){
    union{ unsigned short h4[4]; uint2 u; } pk;
    #pragma unroll
    for (int r=0;r<4;r++) pk.h4[r] = f2h(O[dt][r]);
    *(uint2*)(cb + dt*16) = pk.u;
  }
}

// ---------------------------------------------------------------------------
// LayerNorm over D=512; one wave per row; optional fp16 copy
// ---------------------------------------------------------------------------
__global__ __launch_bounds__(256) void ln_kernel(
    const float* __restrict__ in, const float* __restrict__ g,
    const float* __restrict__ b, float* __restrict__ outf,
    unsigned short* __restrict__ outb)
{
  const int row = blockIdx.x*4 + (threadIdx.x>>6);
  const int l = threadIdx.x & 63;
  const float* p = in + (size_t)row*DM + l*8;
  float4 v0 = *(const float4*)p;
  float4 v1 = *(const float4*)(p+4);
  float vals[8] = {v0.x,v0.y,v0.z,v0.w,v1.x,v1.y,v1.z,v1.w};
  float s = 0.f, q = 0.f;
  #pragma unroll
  for (int j=0;j<8;j++){ s += vals[j]; q += vals[j]*vals[j]; }
  #pragma unroll
  for (int o=1;o<64;o<<=1){ s += __shfl_xor(s,o,64); q += __shfl_xor(q,o,64); }
  const float mu = s*(1.0f/DM);
  const float var = q*(1.0f/DM) - mu*mu;
  const float rs = rsqrtf(var + 1e-6f);
  const float* gp = g + l*8;
  const float* bp = b + l*8;
  float4 g0 = *(const float4*)gp, g1 = *(const float4*)(gp+4);
  float4 bb0 = *(const float4*)bp, bb1 = *(const float4*)(bp+4);
  float gv[8] = {g0.x,g0.y,g0.z,g0.w,g1.x,g1.y,g1.z,g1.w};
  float bv[8] = {bb0.x,bb0.y,bb0.z,bb0.w,bb1.x,bb1.y,bb1.z,bb1.w};
  float ov[8];
  #pragma unroll
  for (int j=0;j<8;j++) ov[j] = (vals[j]-mu)*rs*gv[j] + bv[j];
  float* op = outf + (size_t)row*DM + l*8;
  *(float4*)op     = make_float4(ov[0],ov[1],ov[2],ov[3]);
  *(float4*)(op+4) = make_float4(ov[4],ov[5],ov[6],ov[7]);
  if (outb){
    union{ unsigned short h[8]; uint4 v; } pk;
    #pragma unroll
    for (int j=0;j<8;j++) pk.h[j] = f2h(ov[j]);
    *(uint4*)(outb + (size_t)row*DM + l*8) = pk.v;
  }
}

// ---------------------------------------------------------------------------
extern "C" void kernel_launch(void* const* d_in, const int* in_sizes, int n_in,
                              void* d_out, int out_size, void* d_ws, size_t ws_size,
                              hipStream_t stream)
{
  const float* x    = (const float*)d_in[0];
  // d_in[1] sensor_weights, d_in[8] sensor_attention, d_in[9] temporal_bias:
  // constant along the softmax axis -> exactly cancel in softmax; unused.
  const int*   mask = (const int*)d_in[2];
  const float* Wq   = (const float*)d_in[3];
  const float* Wk   = (const float*)d_in[4];
  const float* Wv   = (const float*)d_in[5];
  const float* Wo   = (const float*)d_in[6];
  const float* bo   = (const float*)d_in[7];
  const float* ln1g = (const float*)d_in[10];
  const float* ln1b = (const float*)d_in[11];
  const float* ln2g = (const float*)d_in[12];
  const float* ln2b = (const float*)d_in[13];
  const float* W1   = (const float*)d_in[14];
  const float* b1   = (const float*)d_in[15];
  const float* W2   = (const float*)d_in[16];
  const float* b2   = (const float*)d_in[17];

  float* x2_out   = (float*)d_out;
  float* attn_out = x2_out + (size_t)NROWS*DM;   // 2,097,152 floats offset

  char* p = (char*)d_ws;
  auto alloc = [&](size_t bytes)->char*{
    char* r = p; p += (bytes + 255) & ~(size_t)255; return r;
  };
  unsigned short* xb   = (unsigned short*)alloc((size_t)NROWS*DM*2);
  unsigned short* wqT  = (unsigned short*)alloc(512*512*2);
  unsigned short* wkT  = (unsigned short*)alloc(512*512*2);
  unsigned short* wvT  = (unsigned short*)alloc(512*512*2);
  unsigned short* woT  = (unsigned short*)alloc(512*512*2);
  unsigned short* w1T  = (unsigned short*)alloc(2048*512*2);
  unsigned short* w2T  = (unsigned short*)alloc(512*2048*2);
  unsigned short* q_ws = (unsigned short*)alloc((size_t)BHN*S_LEN*DK*2);
  unsigned short* k_ws = (unsigned short*)alloc((size_t)BHN*S_LEN*DK*2);
  unsigned short* v_ws = (unsigned short*)alloc((size_t)BHN*S_LEN*DK*2); // v^T
  unsigned*       maskw= (unsigned*)alloc((size_t)S_LEN*64*4);
  unsigned short* ctxb = (unsigned short*)alloc((size_t)NROWS*DM*2);
  float*          yv   = (float*)alloc((size_t)NROWS*DM*4);
  float*          x1f  = (float*)alloc((size_t)NROWS*DM*4);
  unsigned short* x1b  = (unsigned short*)alloc((size_t)NROWS*DM*2);
  unsigned short* hb   = (unsigned short*)alloc((size_t)NROWS*DFF*2);
  float*          zv   = (float*)alloc((size_t)NROWS*DM*4);

  // 1. prep: weight transpose->fp16, x->fp16, mask bitpack
  prep_kernel<<<dim3(1024,8), 256, 0, stream>>>(
      x, mask, Wq, Wk, Wv, Wo, W1, W2,
      xb, wqT, wkT, wvT, woT, w1T, w2T, maskw);

  // 2. QKV projections (z: 0=Q scaled, 1=K, 2=V transposed)
  gemm_kernel<512,0><<<dim3(64,8,3), 256, 0, stream>>>(
      xb, wqT, wkT, wvT, nullptr, nullptr, nullptr, q_ws, k_ws, v_ws);

  // 3. fused softmax stats + attn probs + P@V
  kattn_kernel<<<dim3(32,16), 256, 0, stream>>>(
      q_ws, k_ws, v_ws, maskw, attn_out, ctxb);

  // 4. output proj + bias + residual -> yv
  gemm_kernel<512,1><<<dim3(64,8), 256, 0, stream>>>(
      ctxb, woT, nullptr, nullptr, bo, x, yv, nullptr, nullptr, nullptr);

  // 5. LN1 -> x1f (fp32) + x1b (fp16)
  ln_kernel<<<1024, 256, 0, stream>>>(yv, ln1g, ln1b, x1f, x1b);

  // 6. FF1 + gelu -> hb (fp16)
  gemm_kernel<512,2><<<dim3(64,32), 256, 0, stream>>>(
      x1b, w1T, nullptr, nullptr, b1, nullptr, nullptr, hb, nullptr, nullptr);

  // 7. FF2 + bias + residual(x1) -> zv
  gemm_kernel<2048,1><<<dim3(64,8), 256, 0, stream>>>(
      hb, w2T, nullptr, nullptr, b2, x1f, zv, nullptr, nullptr, nullptr);

  // 8. LN2 -> x2
  ln_kernel<<<1024, 256, 0, stream>>>(zv, ln2g, ln2b, x2_out, nullptr);

  (void)in_sizes; (void)n_in; (void)out_size; (void)ws_size;
}